// Round 9
// baseline (233.769 us; speedup 1.0000x reference)
//
#include <hip/hip_runtime.h>

// ---------- types & helpers ----------
typedef __attribute__((ext_vector_type(8))) short bf16x8;
typedef __attribute__((ext_vector_type(4))) float f32x4;

__device__ __forceinline__ float bf2f(unsigned short u) {
  unsigned int x = ((unsigned int)u) << 16;
  float f; __builtin_memcpy(&f, &x, 4); return f;
}
__device__ __forceinline__ unsigned short f2bf(float f) {
  unsigned int x; __builtin_memcpy(&x, &f, 4);
  unsigned int lsb = (x >> 16) & 1u;
  x += 0x7fffu + lsb;                 // round-to-nearest-even
  return (unsigned short)(x >> 16);
}
__device__ __forceinline__ unsigned short f2bf_trunc(float f) {
  unsigned int x; __builtin_memcpy(&x, &f, 4);
  return (unsigned short)(x >> 16);   // truncate: P>=0, bias ~2^-9 relative, fine
}
__device__ __forceinline__ float exp2_raw(float x) {
  float r;
  asm("v_exp_f32 %0, %1" : "=v"(r) : "v"(x));  // bare transcendental, no libm fixup
  return r;
}
__device__ __forceinline__ void gload16(const unsigned short* g, unsigned short* l) {
  __builtin_amdgcn_global_load_lds(
      (const __attribute__((address_space(1))) unsigned int*)g,
      (__attribute__((address_space(3))) unsigned int*)l, 16, 0, 0);
}

// ---------- fused f32 -> bf16 convert of x, w_qkv, w_o (one launch) ----------
__global__ __launch_bounds__(256) void cvt3(const float* __restrict__ x,
                                            const float* __restrict__ wq,
                                            const float* __restrict__ wo,
                                            unsigned short* __restrict__ xb,
                                            unsigned short* __restrict__ wqb,
                                            unsigned short* __restrict__ wob) {
  const int N0 = 1048576, N1 = 786432, N2 = 524288;  // 8-elem chunks per tensor
  for (int i = blockIdx.x * 256 + threadIdx.x; i < N0 + N1 + N2;
       i += (int)(gridDim.x * 256)) {
    const float* in; unsigned short* out; int j;
    if (i < N0)            { in = x;  out = xb;  j = i; }
    else if (i < N0 + N1)  { in = wq; out = wqb; j = i - N0; }
    else                   { in = wo; out = wob; j = i - N0 - N1; }
    const float4* p = (const float4*)(in + (size_t)j * 8);
    float4 a = p[0], b = p[1];
    union { bf16x8 v; unsigned short u[8]; } o;
    o.u[0] = f2bf(a.x); o.u[1] = f2bf(a.y); o.u[2] = f2bf(a.z); o.u[3] = f2bf(a.w);
    o.u[4] = f2bf(b.x); o.u[5] = f2bf(b.y); o.u[6] = f2bf(b.z); o.u[7] = f2bf(b.w);
    *(bf16x8*)(out + (size_t)j * 8) = o.v;
  }
}

// ---------- GEMM: C[M,N] = A[M,2048] * B[N,2048]^T  (bf16 in, bf16 or f32 out) ----------
template <int F32OUT>
__global__ __launch_bounds__(256) void gemm_bt(const unsigned short* __restrict__ A,
                                               const unsigned short* __restrict__ B,
                                               void* __restrict__ Cp, int N) {
  __shared__ unsigned short sA[128 * 32];
  __shared__ unsigned short sB[128 * 32];
  const int t = threadIdx.x;
  const int lane = t & 63, w = t >> 6;
  const int wm = w >> 1, wn = w & 1;
  const int l16 = lane & 15, hi = lane >> 4;
  const int m0 = blockIdx.y * 128, n0 = blockIdx.x * 128;

  f32x4 zero = {0.f, 0.f, 0.f, 0.f};
  f32x4 acc[4][4];
#pragma unroll
  for (int mi = 0; mi < 4; ++mi)
#pragma unroll
    for (int ni = 0; ni < 4; ++ni) acc[mi][ni] = zero;

  const int srow = t >> 2;
  const int scol = (t & 3) * 8;
  const unsigned short* gA0 = A + (size_t)(m0 + srow) * 2048 + scol;
  const unsigned short* gB0 = B + (size_t)(n0 + srow) * 2048 + scol;

  int offA[4], offB[4];
#pragma unroll
  for (int i = 0; i < 4; ++i) {
    offA[i] = (wm * 64 + i * 16 + l16) * 32 + hi * 8;
    offB[i] = (wn * 64 + i * 16 + l16) * 32 + hi * 8;
  }

  for (int k0 = 0; k0 < 2048; k0 += 32) {
    __syncthreads();
    gload16(gA0 + k0, &sA[t * 8]);
    gload16(gA0 + (size_t)64 * 2048 + k0, &sA[2048 + t * 8]);
    gload16(gB0 + k0, &sB[t * 8]);
    gload16(gB0 + (size_t)64 * 2048 + k0, &sB[2048 + t * 8]);
    __syncthreads();
    bf16x8 af[4], bfr[4];
#pragma unroll
    for (int i = 0; i < 4; ++i) af[i] = *(const bf16x8*)&sA[offA[i]];
#pragma unroll
    for (int i = 0; i < 4; ++i) bfr[i] = *(const bf16x8*)&sB[offB[i]];
#pragma unroll
    for (int mi = 0; mi < 4; ++mi)
#pragma unroll
      for (int ni = 0; ni < 4; ++ni)
        acc[mi][ni] = __builtin_amdgcn_mfma_f32_16x16x32_bf16(af[mi], bfr[ni], acc[mi][ni], 0, 0, 0);
  }

  const int rowb = m0 + wm * 64 + hi * 4;
  const int colb = n0 + wn * 64 + l16;
#pragma unroll
  for (int mi = 0; mi < 4; ++mi)
#pragma unroll
    for (int ni = 0; ni < 4; ++ni)
#pragma unroll
      for (int r = 0; r < 4; ++r) {
        size_t idx = (size_t)(rowb + mi * 16 + r) * N + colb + ni * 16;
        if (F32OUT) ((float*)Cp)[idx] = acc[mi][ni][r];
        else        ((unsigned short*)Cp)[idx] = f2bf(acc[mi][ni][r]);
      }
}

// ---------- RoPE on q,k heads; scatter to [B,H,L,64] ----------
// q additionally pre-scaled by (1/8)*log2(e) so attention can use exp2 directly.
__global__ __launch_bounds__(256) void rope_qk(const unsigned short* __restrict__ qkv,
                                               unsigned short* __restrict__ q,
                                               unsigned short* __restrict__ k) {
  int tid = blockIdx.x * 256 + threadIdx.x;  // 2*40*2048 = 163840 threads
  int l = tid & 2047;
  int rest = tid >> 11;
  int b = rest & 1;
  int h = rest >> 1;  // 0..39 (0..31 q, 32..39 k)
  const unsigned short* src = qkv + (size_t)(b * 2048 + l) * 3072 + h * 64;
  union { uint4 v[8]; unsigned short u[64]; } buf;
#pragma unroll
  for (int i = 0; i < 8; ++i) buf.v[i] = ((const uint4*)src)[i];
  const float sc = (h < 32) ? 0.125f * 1.44269504088896f : 1.0f;
#pragma unroll
  for (int j = 0; j < 32; ++j) {
    float fr = exp2f(-(float)j * 0.41524101186092033f);  // log2(10000)/32
    float ang = (float)l * fr;
    float sn, cs;
    sincosf(ang, &sn, &cs);
    float x0 = bf2f(buf.u[2 * j]), x1 = bf2f(buf.u[2 * j + 1]);
    float y0 = (x0 * cs - x1 * sn) * sc;
    float y1 = (x1 * cs + x0 * sn) * sc;
    buf.u[2 * j] = f2bf(y0);
    buf.u[2 * j + 1] = f2bf(y1);
  }
  unsigned short* dst = (h < 32) ? (q + ((size_t)(b * 32 + h) * 2048 + l) * 64)
                                 : (k + ((size_t)(b * 8 + h - 32) * 2048 + l) * 64);
#pragma unroll
  for (int i = 0; i < 8; ++i) ((uint4*)dst)[i] = buf.v[i];
}

// ---------- V transpose: qkv v-heads -> VT[B,8,64,L] ----------
__global__ __launch_bounds__(256) void vtrans(const unsigned short* __restrict__ qkv,
                                              unsigned short* __restrict__ vt) {
  __shared__ unsigned short sT[64 * 72];
  const int t = threadIdx.x;
  const int bh = blockIdx.y;  // 0..15
  const int b = bh >> 3, h = bh & 7;
  const int l0 = blockIdx.x * 64;
  const int c = t & 7, i0 = t >> 3;  // c: d-chunk, i0: 0..31
#pragma unroll
  for (int pp = 0; pp < 2; ++pp) {
    int i = i0 + pp * 32;
    const unsigned short* src =
        qkv + (size_t)(b * 2048 + l0 + i) * 3072 + 2560 + h * 64 + c * 8;
    union { bf16x8 v; unsigned short u[8]; } x;
    x.v = *(const bf16x8*)src;
#pragma unroll
    for (int e = 0; e < 8; ++e) sT[(c * 8 + e) * 72 + i] = x.u[e];
  }
  __syncthreads();
  const int d = t >> 2, ic = (t & 3) * 16;
  unsigned short* dst = vt + ((size_t)(b * 8 + h) * 64 + d) * 2048 + l0 + ic;
  *(bf16x8*)dst = *(const bf16x8*)&sT[d * 72 + ic];
  *(bf16x8*)(dst + 8) = *(const bf16x8*)&sT[d * 72 + ic + 8];
}

// ---------- one 128-col KV step for one 32-row q-tile (QK^T -> exp -> P -> PV) ----------
__device__ __forceinline__ void attn_step(const unsigned short* __restrict__ sK,
                                          const unsigned short* __restrict__ sV,
                                          unsigned short* __restrict__ sPw,
                                          const bf16x8 (&qf)[2][2],
                                          f32x4 (&o)[2][4], float (&lsum)[2][4],
                                          int q0, int c0, int l16, int hi) {
  f32x4 zero = {0.f, 0.f, 0.f, 0.f};
  // --- two 64-col halves: QK^T + exp -> P in LDS ---
#pragma unroll
  for (int h = 0; h < 2; ++h) {
    const int c0h = c0 + h * 64;
    if (c0h > q0) break;  // fully-masked half for this wave
    f32x4 sc[2][4];
#pragma unroll
    for (int mi = 0; mi < 2; ++mi)
#pragma unroll
      for (int ni = 0; ni < 4; ++ni) sc[mi][ni] = zero;
#pragma unroll
    for (int ni = 0; ni < 4; ++ni) {
      const int krow = h * 64 + ni * 16 + l16;
      bf16x8 k0f = *(const bf16x8*)&sK[krow * 64 + ((hi ^ (l16 & 7)) * 8)];
      bf16x8 k1f = *(const bf16x8*)&sK[krow * 64 + (((4 + hi) ^ (l16 & 7)) * 8)];
#pragma unroll
      for (int mi = 0; mi < 2; ++mi) {
        sc[mi][ni] = __builtin_amdgcn_mfma_f32_16x16x32_bf16(qf[mi][0], k0f, sc[mi][ni], 0, 0, 0);
        sc[mi][ni] = __builtin_amdgcn_mfma_f32_16x16x32_bf16(qf[mi][1], k1f, sc[mi][ni], 0, 0, 0);
      }
    }
    if (c0h + 64 > q0) {  // boundary half: per-element causal mask
#pragma unroll
      for (int mi = 0; mi < 2; ++mi)
#pragma unroll
        for (int ni = 0; ni < 4; ++ni)
#pragma unroll
          for (int r = 0; r < 4; ++r) {
            int col = c0h + ni * 16 + l16;
            int row = q0 + mi * 16 + hi * 4 + r;
            if (col > row) sc[mi][ni][r] = -1e30f;
          }
    }
#pragma unroll
    for (int mi = 0; mi < 2; ++mi)
#pragma unroll
      for (int ni = 0; ni < 4; ++ni)
#pragma unroll
        for (int r = 0; r < 4; ++r) {
          float p = exp2_raw(sc[mi][ni][r]);
          lsum[mi][r] += p;
          sPw[(mi * 16 + hi * 4 + r) * 136 + h * 64 + ni * 16 + l16] = f2bf_trunc(p);
        }
  }
  // --- PV over the 128 cols (only valid 32-col quarters for this wave) ---
#pragma unroll
  for (int ks = 0; ks < 4; ++ks) {
    if (c0 + ks * 32 > q0) break;  // wave-uniform
    bf16x8 pa[2];
#pragma unroll
    for (int mi = 0; mi < 2; ++mi)
      pa[mi] = *(const bf16x8*)&sPw[(mi * 16 + l16) * 136 + ks * 32 + hi * 8];
#pragma unroll
    for (int ni = 0; ni < 4; ++ni) {
      const int d = ni * 16 + l16;
      bf16x8 vb = *(const bf16x8*)&sV[d * 128 + (((ks * 4 + hi) ^ l16) * 8)];
#pragma unroll
      for (int mi = 0; mi < 2; ++mi)
        o[mi][ni] = __builtin_amdgcn_mfma_f32_16x16x32_bf16(pa[mi], vb, o[mi][ni], 0, 0, 0);
    }
  }
}

// ---------- GQA causal flash attention (two 128-row Q-blocks share staged K/V) ----------
// Q[B,32,L,64] (pre-scaled by 0.125*log2e), K[B,8,L,64], VT[B,8,64,L] -> Y[B,L,2048] bf16
// Each block owns q-blocks A=pi and B=15-pi and stages each 128-col K/V tile into
// LDS ONCE for both (tiles 0..15-pi). Compute is uniform: every block does exactly
// 17 wave-steps (A: pi+1, B: 16-pi). Staging avg 12.5 tiles/block (was 17).
__global__ __launch_bounds__(256) void attn(const unsigned short* __restrict__ Q,
                                            const unsigned short* __restrict__ K,
                                            const unsigned short* __restrict__ VT,
                                            unsigned short* __restrict__ Y) {
  __shared__ unsigned short sK[128 * 64];   // 16 KB, row-major, chunk^=(row&7)
  __shared__ unsigned short sV[64 * 128];   // 16 KB, [d][col], chunk^=(d&15)
  __shared__ unsigned short sP[4][32 * 136];
  const int t = threadIdx.x, lane = t & 63, w = t >> 6;
  const int l16 = lane & 15, hi = lane >> 4;
  const int pi = blockIdx.y;     // 0..7
  const int head = blockIdx.x;   // 0..63
  const int b = head >> 5, hq = head & 31, hkv = hq >> 2;
  const unsigned short* kp = K + (size_t)(b * 8 + hkv) * 2048 * 64;
  const unsigned short* vp = VT + (size_t)(b * 8 + hkv) * 64 * 2048;
  unsigned short* sPw = sP[w];
  f32x4 zero = {0.f, 0.f, 0.f, 0.f};

  const int q0A = pi * 128 + w * 32;         // light q-tile
  const int q0B = (15 - pi) * 128 + w * 32;  // heavy q-tile
  const unsigned short* qpA = Q + ((size_t)(b * 32 + hq) * 2048 + q0A) * 64;
  const unsigned short* qpB = Q + ((size_t)(b * 32 + hq) * 2048 + q0B) * 64;

  bf16x8 qfA[2][2], qfB[2][2];
#pragma unroll
  for (int mi = 0; mi < 2; ++mi)
#pragma unroll
    for (int ks = 0; ks < 2; ++ks) {
      qfA[mi][ks] = *(const bf16x8*)(qpA + (size_t)(mi * 16 + l16) * 64 + ks * 32 + hi * 8);
      qfB[mi][ks] = *(const bf16x8*)(qpB + (size_t)(mi * 16 + l16) * 64 + ks * 32 + hi * 8);
    }

  f32x4 oA[2][4], oB[2][4];
  float lsA[2][4], lsB[2][4];
#pragma unroll
  for (int mi = 0; mi < 2; ++mi) {
#pragma unroll
    for (int ni = 0; ni < 4; ++ni) { oA[mi][ni] = zero; oB[mi][ni] = zero; }
#pragma unroll
    for (int r = 0; r < 4; ++r) { lsA[mi][r] = 0.f; lsB[mi][r] = 0.f; }
  }

  const int ntt = 16 - pi;  // staged 128-col KV tiles (covers both q-blocks)
  for (int tt = 0; tt < ntt; ++tt) {
    const int c0 = tt * 128;
    __syncthreads();  // prior step's sK/sV reads complete before overwrite
    // --- cooperative staging, pre-swizzled global source, linear LDS dest ---
#pragma unroll
    for (int i = 0; i < 4; ++i) {
      int c = i * 256 + t;                 // K chunk 0..1023 (16B each)
      int row = c >> 3, cb = c & 7;
      gload16(kp + (size_t)(c0 + row) * 64 + ((cb ^ (row & 7)) * 8), &sK[c * 8]);
    }
#pragma unroll
    for (int i = 0; i < 4; ++i) {
      int c = i * 256 + t;                 // V chunk 0..1023
      int d = c >> 4, cb = c & 15;
      gload16(vp + (size_t)d * 2048 + c0 + ((cb ^ (d & 15)) * 8), &sV[c * 8]);
    }
    __syncthreads();  // staged tile visible

    if (tt <= pi)  // q-block A still consuming tiles (block-uniform branch)
      attn_step(sK, sV, sPw, qfA, oA, lsA, q0A, c0, l16, hi);
    attn_step(sK, sV, sPw, qfB, oB, lsB, q0B, c0, l16, hi);
  }

  // ---- epilogues: reduce row-sums, normalize, store ----
#pragma unroll
  for (int e = 0; e < 2; ++e) {
    f32x4 (&o)[2][4] = e ? oB : oA;
    float (&ls)[2][4] = e ? lsB : lsA;
    const int q0 = e ? q0B : q0A;
#pragma unroll
    for (int mi = 0; mi < 2; ++mi) {
#pragma unroll
      for (int msk = 1; msk <= 8; msk <<= 1)
#pragma unroll
        for (int r = 0; r < 4; ++r) ls[mi][r] += __shfl_xor(ls[mi][r], msk);
      float inv[4];
#pragma unroll
      for (int r = 0; r < 4; ++r) inv[r] = 1.f / ls[mi][r];
#pragma unroll
      for (int ni = 0; ni < 4; ++ni)
#pragma unroll
        for (int r = 0; r < 4; ++r) {
          int row = q0 + mi * 16 + hi * 4 + r;
          Y[(size_t)(b * 2048 + row) * 2048 + hq * 64 + ni * 16 + l16] =
              f2bf(o[mi][ni][r] * inv[r]);
        }
    }
  }
}

// ---------- launcher ----------
extern "C" void kernel_launch(void* const* d_in, const int* in_sizes, int n_in,
                              void* d_out, int out_size, void* d_ws, size_t ws_size,
                              hipStream_t stream) {
  const float* x    = (const float*)d_in[0];   // [2,2048,2048]
  const float* wqkv = (const float*)d_in[1];   // [3072,2048]
  const float* wo   = (const float*)d_in[2];   // [2048,2048]
  float* out = (float*)d_out;                  // [2,2048,2048] f32

  char* ws = (char*)d_ws;
  unsigned short* xb   = (unsigned short*)(ws);              // [0, 16M)  x bf16; later y
  unsigned short* wqb  = (unsigned short*)(ws + 16777216);   // dead after gemm1
  unsigned short* wob  = (unsigned short*)(ws + 29360128);
  unsigned short* qkvb = (unsigned short*)(ws + 37748736);   // dead after vtrans
  unsigned short* qb   = (unsigned short*)(ws + 62914560);
  unsigned short* kb   = (unsigned short*)(ws + 79691776);
  unsigned short* vtb  = (unsigned short*)(ws + 83886080);   // total 88,080,384
  unsigned short* yb = xb;  // alias: x's bf16 copy is dead after the QKV GEMM

  cvt3<<<2048, 256, 0, stream>>>(x, wqkv, wo, xb, wqb, wob);
  gemm_bt<0><<<dim3(3072 / 128, 4096 / 128), 256, 0, stream>>>(xb, wqb, qkvb, 3072);
  rope_qk<<<640, 256, 0, stream>>>(qkvb, qb, kb);
  vtrans<<<dim3(32, 16), 256, 0, stream>>>(qkvb, vtb);
  attn<<<dim3(64, 8), 256, 0, stream>>>(qb, kb, vtb, yb);
  gemm_bt<1><<<dim3(2048 / 128, 4096 / 128), 256, 0, stream>>>(yb, wob, out, 2048);
}

// Round 10
// 208.698 us; speedup vs baseline: 1.1201x; 1.1201x over previous
//
#include <hip/hip_runtime.h>

// ---------- types & helpers ----------
typedef __attribute__((ext_vector_type(8))) short bf16x8;
typedef __attribute__((ext_vector_type(4))) float f32x4;

__device__ __forceinline__ float bf2f(unsigned short u) {
  unsigned int x = ((unsigned int)u) << 16;
  float f; __builtin_memcpy(&f, &x, 4); return f;
}
__device__ __forceinline__ unsigned short f2bf(float f) {
  unsigned int x; __builtin_memcpy(&x, &f, 4);
  unsigned int lsb = (x >> 16) & 1u;
  x += 0x7fffu + lsb;                 // round-to-nearest-even
  return (unsigned short)(x >> 16);
}
__device__ __forceinline__ unsigned short f2bf_trunc(float f) {
  unsigned int x; __builtin_memcpy(&x, &f, 4);
  return (unsigned short)(x >> 16);   // truncate: P>=0, bias ~2^-9 relative, fine
}
__device__ __forceinline__ float exp2_raw(float x) {
  float r;
  asm("v_exp_f32 %0, %1" : "=v"(r) : "v"(x));  // bare transcendental, no libm fixup
  return r;
}
__device__ __forceinline__ void gload16(const unsigned short* g, unsigned short* l) {
  __builtin_amdgcn_global_load_lds(
      (const __attribute__((address_space(1))) unsigned int*)g,
      (__attribute__((address_space(3))) unsigned int*)l, 16, 0, 0);
}

// ---------- fused f32 -> bf16 convert of x, w_qkv, w_o (one launch) ----------
__global__ __launch_bounds__(256) void cvt3(const float* __restrict__ x,
                                            const float* __restrict__ wq,
                                            const float* __restrict__ wo,
                                            unsigned short* __restrict__ xb,
                                            unsigned short* __restrict__ wqb,
                                            unsigned short* __restrict__ wob) {
  const int N0 = 1048576, N1 = 786432, N2 = 524288;  // 8-elem chunks per tensor
  for (int i = blockIdx.x * 256 + threadIdx.x; i < N0 + N1 + N2;
       i += (int)(gridDim.x * 256)) {
    const float* in; unsigned short* out; int j;
    if (i < N0)            { in = x;  out = xb;  j = i; }
    else if (i < N0 + N1)  { in = wq; out = wqb; j = i - N0; }
    else                   { in = wo; out = wob; j = i - N0 - N1; }
    const float4* p = (const float4*)(in + (size_t)j * 8);
    float4 a = p[0], b = p[1];
    union { bf16x8 v; unsigned short u[8]; } o;
    o.u[0] = f2bf(a.x); o.u[1] = f2bf(a.y); o.u[2] = f2bf(a.z); o.u[3] = f2bf(a.w);
    o.u[4] = f2bf(b.x); o.u[5] = f2bf(b.y); o.u[6] = f2bf(b.z); o.u[7] = f2bf(b.w);
    *(bf16x8*)(out + (size_t)j * 8) = o.v;
  }
}

// ---------- GEMM: C[M,N] = A[M,2048] * B[N,2048]^T  (bf16 in, bf16 or f32 out) ----------
template <int F32OUT>
__global__ __launch_bounds__(256) void gemm_bt(const unsigned short* __restrict__ A,
                                               const unsigned short* __restrict__ B,
                                               void* __restrict__ Cp, int N) {
  __shared__ unsigned short sA[128 * 32];
  __shared__ unsigned short sB[128 * 32];
  const int t = threadIdx.x;
  const int lane = t & 63, w = t >> 6;
  const int wm = w >> 1, wn = w & 1;
  const int l16 = lane & 15, hi = lane >> 4;
  const int m0 = blockIdx.y * 128, n0 = blockIdx.x * 128;

  f32x4 zero = {0.f, 0.f, 0.f, 0.f};
  f32x4 acc[4][4];
#pragma unroll
  for (int mi = 0; mi < 4; ++mi)
#pragma unroll
    for (int ni = 0; ni < 4; ++ni) acc[mi][ni] = zero;

  const int srow = t >> 2;
  const int scol = (t & 3) * 8;
  const unsigned short* gA0 = A + (size_t)(m0 + srow) * 2048 + scol;
  const unsigned short* gB0 = B + (size_t)(n0 + srow) * 2048 + scol;

  int offA[4], offB[4];
#pragma unroll
  for (int i = 0; i < 4; ++i) {
    offA[i] = (wm * 64 + i * 16 + l16) * 32 + hi * 8;
    offB[i] = (wn * 64 + i * 16 + l16) * 32 + hi * 8;
  }

  for (int k0 = 0; k0 < 2048; k0 += 32) {
    __syncthreads();
    gload16(gA0 + k0, &sA[t * 8]);
    gload16(gA0 + (size_t)64 * 2048 + k0, &sA[2048 + t * 8]);
    gload16(gB0 + k0, &sB[t * 8]);
    gload16(gB0 + (size_t)64 * 2048 + k0, &sB[2048 + t * 8]);
    __syncthreads();
    bf16x8 af[4], bfr[4];
#pragma unroll
    for (int i = 0; i < 4; ++i) af[i] = *(const bf16x8*)&sA[offA[i]];
#pragma unroll
    for (int i = 0; i < 4; ++i) bfr[i] = *(const bf16x8*)&sB[offB[i]];
#pragma unroll
    for (int mi = 0; mi < 4; ++mi)
#pragma unroll
      for (int ni = 0; ni < 4; ++ni)
        acc[mi][ni] = __builtin_amdgcn_mfma_f32_16x16x32_bf16(af[mi], bfr[ni], acc[mi][ni], 0, 0, 0);
  }

  const int rowb = m0 + wm * 64 + hi * 4;
  const int colb = n0 + wn * 64 + l16;
#pragma unroll
  for (int mi = 0; mi < 4; ++mi)
#pragma unroll
    for (int ni = 0; ni < 4; ++ni)
#pragma unroll
      for (int r = 0; r < 4; ++r) {
        size_t idx = (size_t)(rowb + mi * 16 + r) * N + colb + ni * 16;
        if (F32OUT) ((float*)Cp)[idx] = acc[mi][ni][r];
        else        ((unsigned short*)Cp)[idx] = f2bf(acc[mi][ni][r]);
      }
}

// ---------- fused prep: RoPE(q,k) scatter + V transpose (one launch) ----------
// blocks 0..639: RoPE; blocks 640..1151: V transpose.
__global__ __launch_bounds__(256) void prep(const unsigned short* __restrict__ qkv,
                                            unsigned short* __restrict__ q,
                                            unsigned short* __restrict__ k,
                                            unsigned short* __restrict__ vt) {
  __shared__ unsigned short sT[64 * 72];
  const int bid = blockIdx.x;
  if (bid < 640) {
    // ---- RoPE on q,k heads; q pre-scaled by (1/8)*log2(e) for exp2 softmax ----
    int tid = bid * 256 + threadIdx.x;  // 2*40*2048 = 163840 threads
    int l = tid & 2047;
    int rest = tid >> 11;
    int b = rest & 1;
    int h = rest >> 1;  // 0..39 (0..31 q, 32..39 k)
    const unsigned short* src = qkv + (size_t)(b * 2048 + l) * 3072 + h * 64;
    union { uint4 v[8]; unsigned short u[64]; } buf;
#pragma unroll
    for (int i = 0; i < 8; ++i) buf.v[i] = ((const uint4*)src)[i];
    const float sc = (h < 32) ? 0.125f * 1.44269504088896f : 1.0f;
#pragma unroll
    for (int j = 0; j < 32; ++j) {
      float fr = exp2f(-(float)j * 0.41524101186092033f);  // log2(10000)/32
      float ang = (float)l * fr;
      float sn, cs;
      sincosf(ang, &sn, &cs);
      float x0 = bf2f(buf.u[2 * j]), x1 = bf2f(buf.u[2 * j + 1]);
      float y0 = (x0 * cs - x1 * sn) * sc;
      float y1 = (x1 * cs + x0 * sn) * sc;
      buf.u[2 * j] = f2bf(y0);
      buf.u[2 * j + 1] = f2bf(y1);
    }
    unsigned short* dst = (h < 32) ? (q + ((size_t)(b * 32 + h) * 2048 + l) * 64)
                                   : (k + ((size_t)(b * 8 + h - 32) * 2048 + l) * 64);
#pragma unroll
    for (int i = 0; i < 8; ++i) ((uint4*)dst)[i] = buf.v[i];
  } else {
    // ---- V transpose: qkv v-heads -> VT[B,8,64,L] ----
    const int bid2 = bid - 640;        // 0..511
    const int xb = bid2 & 31, bh = bid2 >> 5;
    const int t = threadIdx.x;
    const int b = bh >> 3, h = bh & 7;
    const int l0 = xb * 64;
    const int c = t & 7, i0 = t >> 3;  // c: d-chunk, i0: 0..31
#pragma unroll
    for (int pp = 0; pp < 2; ++pp) {
      int i = i0 + pp * 32;
      const unsigned short* src =
          qkv + (size_t)(b * 2048 + l0 + i) * 3072 + 2560 + h * 64 + c * 8;
      union { bf16x8 v; unsigned short u[8]; } x;
      x.v = *(const bf16x8*)src;
#pragma unroll
      for (int e = 0; e < 8; ++e) sT[(c * 8 + e) * 72 + i] = x.u[e];
    }
    __syncthreads();
    const int d = t >> 2, ic = (t & 3) * 16;
    unsigned short* dst = vt + ((size_t)(b * 8 + h) * 64 + d) * 2048 + l0 + ic;
    *(bf16x8*)dst = *(const bf16x8*)&sT[d * 72 + ic];
    *(bf16x8*)(dst + 8) = *(const bf16x8*)&sT[d * 72 + ic + 8];
  }
}

// ---------- GQA causal flash attention (128-row Q-block, LDS-shared K/V) ----------
// Q[B,32,L,64] (pre-scaled by 0.125*log2e), K[B,8,L,64], VT[B,8,64,L] -> Y[B,L,2048] bf16
// Stage each 128-col K/V tile into LDS ONCE per 128-row Q-block (4 waves share).
// XOR-swizzled staging (pre-swizzled global source, linear LDS dest). Block
// pairing (qb = pi and 15-pi) gives uniform 17 steps/block. XCD head remap:
// the 4 q-heads sharing one kv-head (+ all their pi-blocks) land on ONE XCD,
// so each XCD's L2 holds 8 heads' Q (2MB) + 2 kv-heads' K/V (1MB).
__global__ __launch_bounds__(256) void attn(const unsigned short* __restrict__ Q,
                                            const unsigned short* __restrict__ K,
                                            const unsigned short* __restrict__ VT,
                                            unsigned short* __restrict__ Y) {
  __shared__ unsigned short sK[128 * 64];   // 16 KB, row-major, chunk^=(row&7)
  __shared__ unsigned short sV[64 * 128];   // 16 KB, [d][col], chunk^=(d&15)
  __shared__ unsigned short sP[4][32 * 136];
  const int t = threadIdx.x, lane = t & 63, w = t >> 6;
  const int l16 = lane & 15, hi = lane >> 4;
  const int pi = blockIdx.y;     // 0..7
  const int bx = blockIdx.x;     // 0..63
  const int head = ((bx & 7) << 3) | (bx >> 3);  // XCD-pinning permutation
  const int b = head >> 5, hq = head & 31, hkv = hq >> 2;
  const unsigned short* kp = K + (size_t)(b * 8 + hkv) * 2048 * 64;
  const unsigned short* vp = VT + (size_t)(b * 8 + hkv) * 64 * 2048;
  unsigned short* sPw = sP[w];
  f32x4 zero = {0.f, 0.f, 0.f, 0.f};

#pragma unroll
  for (int phase = 0; phase < 2; ++phase) {
    const int qb = phase ? (15 - pi) : pi;   // q-block index, 128 rows
    const int q0 = qb * 128 + w * 32;        // this wave's 32-row tile base
    const unsigned short* qp = Q + ((size_t)(b * 32 + hq) * 2048 + q0) * 64;

    bf16x8 qf[2][2];
#pragma unroll
    for (int mi = 0; mi < 2; ++mi)
#pragma unroll
      for (int ks = 0; ks < 2; ++ks)
        qf[mi][ks] = *(const bf16x8*)(qp + (size_t)(mi * 16 + l16) * 64 + ks * 32 + hi * 8);

    f32x4 o[2][4];
    float lsum[2][4];
#pragma unroll
    for (int mi = 0; mi < 2; ++mi) {
#pragma unroll
      for (int ni = 0; ni < 4; ++ni) o[mi][ni] = zero;
#pragma unroll
      for (int r = 0; r < 4; ++r) lsum[mi][r] = 0.f;
    }

    const int nt = qb + 1;  // 128-col KV tiles (block-uniform)
    for (int tt = 0; tt < nt; ++tt) {
      const int c0 = tt * 128;
      __syncthreads();  // prior step's sK/sV reads complete before overwrite
      // --- cooperative staging, pre-swizzled global source, linear LDS dest ---
#pragma unroll
      for (int i = 0; i < 4; ++i) {
        int c = i * 256 + t;                 // K chunk 0..1023 (16B each)
        int row = c >> 3, cb = c & 7;
        gload16(kp + (size_t)(c0 + row) * 64 + ((cb ^ (row & 7)) * 8), &sK[c * 8]);
      }
#pragma unroll
      for (int i = 0; i < 4; ++i) {
        int c = i * 256 + t;                 // V chunk 0..1023
        int d = c >> 4, cb = c & 15;
        gload16(vp + (size_t)d * 2048 + c0 + ((cb ^ (d & 15)) * 8), &sV[c * 8]);
      }
      __syncthreads();  // staged tile visible (vmcnt drained by barrier)

      // --- two 64-col halves: QK^T + exp -> P in LDS ---
#pragma unroll
      for (int h = 0; h < 2; ++h) {
        const int c0h = c0 + h * 64;
        if (c0h > q0) break;  // fully-masked half for this wave (no barriers inside)
        f32x4 sc[2][4];
#pragma unroll
        for (int mi = 0; mi < 2; ++mi)
#pragma unroll
          for (int ni = 0; ni < 4; ++ni) sc[mi][ni] = zero;
#pragma unroll
        for (int ni = 0; ni < 4; ++ni) {
          const int krow = h * 64 + ni * 16 + l16;
          bf16x8 k0f = *(const bf16x8*)&sK[krow * 64 + ((hi ^ (l16 & 7)) * 8)];
          bf16x8 k1f = *(const bf16x8*)&sK[krow * 64 + (((4 + hi) ^ (l16 & 7)) * 8)];
#pragma unroll
          for (int mi = 0; mi < 2; ++mi) {
            sc[mi][ni] = __builtin_amdgcn_mfma_f32_16x16x32_bf16(qf[mi][0], k0f, sc[mi][ni], 0, 0, 0);
            sc[mi][ni] = __builtin_amdgcn_mfma_f32_16x16x32_bf16(qf[mi][1], k1f, sc[mi][ni], 0, 0, 0);
          }
        }
        if (c0h + 64 > q0) {  // boundary half: per-element causal mask
#pragma unroll
          for (int mi = 0; mi < 2; ++mi)
#pragma unroll
            for (int ni = 0; ni < 4; ++ni)
#pragma unroll
              for (int r = 0; r < 4; ++r) {
                int col = c0h + ni * 16 + l16;
                int row = q0 + mi * 16 + hi * 4 + r;
                if (col > row) sc[mi][ni][r] = -1e30f;
              }
        }
#pragma unroll
        for (int mi = 0; mi < 2; ++mi)
#pragma unroll
          for (int ni = 0; ni < 4; ++ni)
#pragma unroll
            for (int r = 0; r < 4; ++r) {
              float p = exp2_raw(sc[mi][ni][r]);
              lsum[mi][r] += p;
              sPw[(mi * 16 + hi * 4 + r) * 136 + h * 64 + ni * 16 + l16] = f2bf_trunc(p);
            }
      }
      // --- PV over the 128 cols (only valid 32-col quarters for this wave) ---
#pragma unroll
      for (int ks = 0; ks < 4; ++ks) {
        if (c0 + ks * 32 > q0) break;  // wave-uniform
        bf16x8 pa[2];
#pragma unroll
        for (int mi = 0; mi < 2; ++mi)
          pa[mi] = *(const bf16x8*)&sPw[(mi * 16 + l16) * 136 + ks * 32 + hi * 8];
#pragma unroll
        for (int ni = 0; ni < 4; ++ni) {
          const int d = ni * 16 + l16;
          bf16x8 vb = *(const bf16x8*)&sV[d * 128 + (((ks * 4 + hi) ^ l16) * 8)];
#pragma unroll
          for (int mi = 0; mi < 2; ++mi)
            o[mi][ni] = __builtin_amdgcn_mfma_f32_16x16x32_bf16(pa[mi], vb, o[mi][ni], 0, 0, 0);
        }
      }
    }
    // final row-sum reduce across the 16 lanes sharing each row, then normalize+store
#pragma unroll
    for (int mi = 0; mi < 2; ++mi) {
#pragma unroll
      for (int msk = 1; msk <= 8; msk <<= 1)
#pragma unroll
        for (int r = 0; r < 4; ++r) lsum[mi][r] += __shfl_xor(lsum[mi][r], msk);
      float inv[4];
#pragma unroll
      for (int r = 0; r < 4; ++r) inv[r] = 1.f / lsum[mi][r];
#pragma unroll
      for (int ni = 0; ni < 4; ++ni)
#pragma unroll
        for (int r = 0; r < 4; ++r) {
          int row = q0 + mi * 16 + hi * 4 + r;
          Y[(size_t)(b * 2048 + row) * 2048 + hq * 64 + ni * 16 + l16] =
              f2bf(o[mi][ni][r] * inv[r]);
        }
    }
  }
}

// ---------- launcher ----------
extern "C" void kernel_launch(void* const* d_in, const int* in_sizes, int n_in,
                              void* d_out, int out_size, void* d_ws, size_t ws_size,
                              hipStream_t stream) {
  const float* x    = (const float*)d_in[0];   // [2,2048,2048]
  const float* wqkv = (const float*)d_in[1];   // [3072,2048]
  const float* wo   = (const float*)d_in[2];   // [2048,2048]
  float* out = (float*)d_out;                  // [2,2048,2048] f32

  char* ws = (char*)d_ws;
  unsigned short* xb   = (unsigned short*)(ws);              // [0, 16M)  x bf16; later y
  unsigned short* wqb  = (unsigned short*)(ws + 16777216);   // dead after gemm1
  unsigned short* wob  = (unsigned short*)(ws + 29360128);
  unsigned short* qkvb = (unsigned short*)(ws + 37748736);   // dead after prep
  unsigned short* qb   = (unsigned short*)(ws + 62914560);
  unsigned short* kb   = (unsigned short*)(ws + 79691776);
  unsigned short* vtb  = (unsigned short*)(ws + 83886080);   // total 88,080,384
  unsigned short* yb = xb;  // alias: x's bf16 copy is dead after the QKV GEMM

  cvt3<<<2048, 256, 0, stream>>>(x, wqkv, wo, xb, wqb, wob);
  gemm_bt<0><<<dim3(3072 / 128, 4096 / 128), 256, 0, stream>>>(xb, wqb, qkvb, 3072);
  prep<<<1152, 256, 0, stream>>>(qkvb, qb, kb, vtb);
  attn<<<dim3(64, 8), 256, 0, stream>>>(qb, kb, vtb, yb);
  gemm_bt<1><<<dim3(2048 / 128, 4096 / 128), 256, 0, stream>>>(yb, wob, out, 2048);
}

// Round 11
// 199.549 us; speedup vs baseline: 1.1715x; 1.0458x over previous
//
#include <hip/hip_runtime.h>

// ---------- types & helpers ----------
typedef __attribute__((ext_vector_type(8))) short bf16x8;
typedef __attribute__((ext_vector_type(4))) float f32x4;

__device__ __forceinline__ float bf2f(unsigned short u) {
  unsigned int x = ((unsigned int)u) << 16;
  float f; __builtin_memcpy(&f, &x, 4); return f;
}
__device__ __forceinline__ unsigned short f2bf(float f) {
  unsigned int x; __builtin_memcpy(&x, &f, 4);
  unsigned int lsb = (x >> 16) & 1u;
  x += 0x7fffu + lsb;                 // round-to-nearest-even
  return (unsigned short)(x >> 16);
}
__device__ __forceinline__ unsigned short f2bf_trunc(float f) {
  unsigned int x; __builtin_memcpy(&x, &f, 4);
  return (unsigned short)(x >> 16);   // truncate: P>=0, bias ~2^-9 relative, fine
}
__device__ __forceinline__ float exp2_raw(float x) {
  float r;
  asm("v_exp_f32 %0, %1" : "=v"(r) : "v"(x));  // bare transcendental, no libm fixup
  return r;
}
__device__ __forceinline__ void gload16(const unsigned short* g, unsigned short* l) {
  __builtin_amdgcn_global_load_lds(
      (const __attribute__((address_space(1))) unsigned int*)g,
      (__attribute__((address_space(3))) unsigned int*)l, 16, 0, 0);
}

// ---------- fused f32 -> bf16 convert of x, w_qkv, w_o (one launch) ----------
__global__ __launch_bounds__(256) void cvt3(const float* __restrict__ x,
                                            const float* __restrict__ wq,
                                            const float* __restrict__ wo,
                                            unsigned short* __restrict__ xb,
                                            unsigned short* __restrict__ wqb,
                                            unsigned short* __restrict__ wob) {
  const int N0 = 1048576, N1 = 786432, N2 = 524288;  // 8-elem chunks per tensor
  for (int i = blockIdx.x * 256 + threadIdx.x; i < N0 + N1 + N2;
       i += (int)(gridDim.x * 256)) {
    const float* in; unsigned short* out; int j;
    if (i < N0)            { in = x;  out = xb;  j = i; }
    else if (i < N0 + N1)  { in = wq; out = wqb; j = i - N0; }
    else                   { in = wo; out = wob; j = i - N0 - N1; }
    const float4* p = (const float4*)(in + (size_t)j * 8);
    float4 a = p[0], b = p[1];
    union { bf16x8 v; unsigned short u[8]; } o;
    o.u[0] = f2bf(a.x); o.u[1] = f2bf(a.y); o.u[2] = f2bf(a.z); o.u[3] = f2bf(a.w);
    o.u[4] = f2bf(b.x); o.u[5] = f2bf(b.y); o.u[6] = f2bf(b.z); o.u[7] = f2bf(b.w);
    *(bf16x8*)(out + (size_t)j * 8) = o.v;
  }
}

// ---------- GEMM: C[M,N] = A[M,2048] * B[N,2048]^T  (bf16 in, bf16 or f32 out) ----------
// BK=64 (half the barrier events of BK=32) + XOR-swizzled staging:
// pre-swizzled per-lane global source (chunk ^= row&7), linear LDS dest,
// matching XOR on the fragment read -> ~2-way max bank aliasing.
template <int F32OUT>
__global__ __launch_bounds__(256) void gemm_bt(const unsigned short* __restrict__ A,
                                               const unsigned short* __restrict__ B,
                                               void* __restrict__ Cp, int N) {
  __shared__ unsigned short sA[128 * 64];   // 16 KB
  __shared__ unsigned short sB[128 * 64];   // 16 KB
  const int t = threadIdx.x;
  const int lane = t & 63, w = t >> 6;
  const int wm = w >> 1, wn = w & 1;
  const int l16 = lane & 15, hi = lane >> 4;
  const int m0 = blockIdx.y * 128, n0 = blockIdx.x * 128;

  f32x4 zero = {0.f, 0.f, 0.f, 0.f};
  f32x4 acc[4][4];
#pragma unroll
  for (int mi = 0; mi < 4; ++mi)
#pragma unroll
    for (int ni = 0; ni < 4; ++ni) acc[mi][ni] = zero;

  const unsigned short* gA = A + (size_t)m0 * 2048;
  const unsigned short* gB = B + (size_t)n0 * 2048;

  for (int k0 = 0; k0 < 2048; k0 += 64) {
    __syncthreads();
#pragma unroll
    for (int i = 0; i < 4; ++i) {
      int c = i * 256 + t;               // chunk 0..1023 (16B each), 8 chunks/row
      int row = c >> 3, cb = c & 7;
      gload16(gA + (size_t)row * 2048 + k0 + ((cb ^ (row & 7)) * 8), &sA[c * 8]);
    }
#pragma unroll
    for (int i = 0; i < 4; ++i) {
      int c = i * 256 + t;
      int row = c >> 3, cb = c & 7;
      gload16(gB + (size_t)row * 2048 + k0 + ((cb ^ (row & 7)) * 8), &sB[c * 8]);
    }
    __syncthreads();
#pragma unroll
    for (int kk = 0; kk < 2; ++kk) {
      bf16x8 af[4], bfr[4];
#pragma unroll
      for (int i = 0; i < 4; ++i) {
        int rowa = wm * 64 + i * 16 + l16;
        af[i]  = *(const bf16x8*)&sA[rowa * 64 + (((kk * 4 + hi) ^ (l16 & 7)) * 8)];
        int rowb = wn * 64 + i * 16 + l16;
        bfr[i] = *(const bf16x8*)&sB[rowb * 64 + (((kk * 4 + hi) ^ (l16 & 7)) * 8)];
      }
#pragma unroll
      for (int mi = 0; mi < 4; ++mi)
#pragma unroll
        for (int ni = 0; ni < 4; ++ni)
          acc[mi][ni] = __builtin_amdgcn_mfma_f32_16x16x32_bf16(af[mi], bfr[ni], acc[mi][ni], 0, 0, 0);
    }
  }

  const int rowb = m0 + wm * 64 + hi * 4;
  const int colb = n0 + wn * 64 + l16;
#pragma unroll
  for (int mi = 0; mi < 4; ++mi)
#pragma unroll
    for (int ni = 0; ni < 4; ++ni)
#pragma unroll
      for (int r = 0; r < 4; ++r) {
        size_t idx = (size_t)(rowb + mi * 16 + r) * N + colb + ni * 16;
        if (F32OUT) ((float*)Cp)[idx] = acc[mi][ni][r];
        else        ((unsigned short*)Cp)[idx] = f2bf(acc[mi][ni][r]);
      }
}

// ---------- fused prep: RoPE(q,k) scatter + V transpose (one launch) ----------
// blocks 0..639: RoPE; blocks 640..1151: V transpose.
__global__ __launch_bounds__(256) void prep(const unsigned short* __restrict__ qkv,
                                            unsigned short* __restrict__ q,
                                            unsigned short* __restrict__ k,
                                            unsigned short* __restrict__ vt) {
  __shared__ unsigned short sT[64 * 72];
  const int bid = blockIdx.x;
  if (bid < 640) {
    // ---- RoPE on q,k heads; q pre-scaled by (1/8)*log2(e) for exp2 softmax ----
    int tid = bid * 256 + threadIdx.x;  // 2*40*2048 = 163840 threads
    int l = tid & 2047;
    int rest = tid >> 11;
    int b = rest & 1;
    int h = rest >> 1;  // 0..39 (0..31 q, 32..39 k)
    const unsigned short* src = qkv + (size_t)(b * 2048 + l) * 3072 + h * 64;
    union { uint4 v[8]; unsigned short u[64]; } buf;
#pragma unroll
    for (int i = 0; i < 8; ++i) buf.v[i] = ((const uint4*)src)[i];
    const float sc = (h < 32) ? 0.125f * 1.44269504088896f : 1.0f;
#pragma unroll
    for (int j = 0; j < 32; ++j) {
      float fr = exp2f(-(float)j * 0.41524101186092033f);  // log2(10000)/32
      float ang = (float)l * fr;
      float sn, cs;
      sincosf(ang, &sn, &cs);
      float x0 = bf2f(buf.u[2 * j]), x1 = bf2f(buf.u[2 * j + 1]);
      float y0 = (x0 * cs - x1 * sn) * sc;
      float y1 = (x1 * cs + x0 * sn) * sc;
      buf.u[2 * j] = f2bf(y0);
      buf.u[2 * j + 1] = f2bf(y1);
    }
    unsigned short* dst = (h < 32) ? (q + ((size_t)(b * 32 + h) * 2048 + l) * 64)
                                   : (k + ((size_t)(b * 8 + h - 32) * 2048 + l) * 64);
#pragma unroll
    for (int i = 0; i < 8; ++i) ((uint4*)dst)[i] = buf.v[i];
  } else {
    // ---- V transpose: qkv v-heads -> VT[B,8,64,L] ----
    const int bid2 = bid - 640;        // 0..511
    const int xb = bid2 & 31, bh = bid2 >> 5;
    const int t = threadIdx.x;
    const int b = bh >> 3, h = bh & 7;
    const int l0 = xb * 64;
    const int c = t & 7, i0 = t >> 3;  // c: d-chunk, i0: 0..31
#pragma unroll
    for (int pp = 0; pp < 2; ++pp) {
      int i = i0 + pp * 32;
      const unsigned short* src =
          qkv + (size_t)(b * 2048 + l0 + i) * 3072 + 2560 + h * 64 + c * 8;
      union { bf16x8 v; unsigned short u[8]; } x;
      x.v = *(const bf16x8*)src;
#pragma unroll
      for (int e = 0; e < 8; ++e) sT[(c * 8 + e) * 72 + i] = x.u[e];
    }
    __syncthreads();
    const int d = t >> 2, ic = (t & 3) * 16;
    unsigned short* dst = vt + ((size_t)(b * 8 + h) * 64 + d) * 2048 + l0 + ic;
    *(bf16x8*)dst = *(const bf16x8*)&sT[d * 72 + ic];
    *(bf16x8*)(dst + 8) = *(const bf16x8*)&sT[d * 72 + ic + 8];
  }
}

// ---------- GQA causal flash attention (128-row Q-block, LDS-shared K/V) ----------
// Q[B,32,L,64] (pre-scaled by 0.125*log2e), K[B,8,L,64], VT[B,8,64,L] -> Y[B,L,2048] bf16
// K/V staged once per 128-row Q-block; XOR-swizzled staging; block pairing
// (qb = pi, 15-pi) for uniform 17 steps/block; XCD head remap. Row-sums are
// computed by MFMA against a ones-fragment (P·1) -> no per-element VALU adds,
// no epilogue shuffle reduce, and denominator matches the truncated-P numerator.
__global__ __launch_bounds__(256) void attn(const unsigned short* __restrict__ Q,
                                            const unsigned short* __restrict__ K,
                                            const unsigned short* __restrict__ VT,
                                            unsigned short* __restrict__ Y) {
  __shared__ unsigned short sK[128 * 64];   // 16 KB, row-major, chunk^=(row&7)
  __shared__ unsigned short sV[64 * 128];   // 16 KB, [d][col], chunk^=(d&15)
  __shared__ unsigned short sP[4][32 * 136];
  const int t = threadIdx.x, lane = t & 63, w = t >> 6;
  const int l16 = lane & 15, hi = lane >> 4;
  const int pi = blockIdx.y;     // 0..7
  const int bx = blockIdx.x;     // 0..63
  const int head = ((bx & 7) << 3) | (bx >> 3);  // XCD-pinning permutation
  const int b = head >> 5, hq = head & 31, hkv = hq >> 2;
  const unsigned short* kp = K + (size_t)(b * 8 + hkv) * 2048 * 64;
  const unsigned short* vp = VT + (size_t)(b * 8 + hkv) * 64 * 2048;
  unsigned short* sPw = sP[w];
  f32x4 zero = {0.f, 0.f, 0.f, 0.f};
  union { bf16x8 v; unsigned short u[8]; } ones_u;
#pragma unroll
  for (int j = 0; j < 8; ++j) ones_u.u[j] = 0x3F80;  // bf16 1.0
  const bf16x8 ones = ones_u.v;

#pragma unroll
  for (int phase = 0; phase < 2; ++phase) {
    const int qb = phase ? (15 - pi) : pi;   // q-block index, 128 rows
    const int q0 = qb * 128 + w * 32;        // this wave's 32-row tile base
    const unsigned short* qp = Q + ((size_t)(b * 32 + hq) * 2048 + q0) * 64;

    bf16x8 qf[2][2];
#pragma unroll
    for (int mi = 0; mi < 2; ++mi)
#pragma unroll
      for (int ks = 0; ks < 2; ++ks)
        qf[mi][ks] = *(const bf16x8*)(qp + (size_t)(mi * 16 + l16) * 64 + ks * 32 + hi * 8);

    f32x4 o[2][4];
    f32x4 os[2];  // row-sums via P x ones MFMA
#pragma unroll
    for (int mi = 0; mi < 2; ++mi) {
#pragma unroll
      for (int ni = 0; ni < 4; ++ni) o[mi][ni] = zero;
      os[mi] = zero;
    }

    const int nt = qb + 1;  // 128-col KV tiles (block-uniform)
    for (int tt = 0; tt < nt; ++tt) {
      const int c0 = tt * 128;
      __syncthreads();  // prior step's sK/sV reads complete before overwrite
      // --- cooperative staging, pre-swizzled global source, linear LDS dest ---
#pragma unroll
      for (int i = 0; i < 4; ++i) {
        int c = i * 256 + t;                 // K chunk 0..1023 (16B each)
        int row = c >> 3, cb = c & 7;
        gload16(kp + (size_t)(c0 + row) * 64 + ((cb ^ (row & 7)) * 8), &sK[c * 8]);
      }
#pragma unroll
      for (int i = 0; i < 4; ++i) {
        int c = i * 256 + t;                 // V chunk 0..1023
        int d = c >> 4, cb = c & 15;
        gload16(vp + (size_t)d * 2048 + c0 + ((cb ^ (d & 15)) * 8), &sV[c * 8]);
      }
      __syncthreads();  // staged tile visible (vmcnt drained by barrier)

      // --- two 64-col halves: QK^T + exp -> P in LDS ---
#pragma unroll
      for (int h = 0; h < 2; ++h) {
        const int c0h = c0 + h * 64;
        if (c0h > q0) break;  // fully-masked half for this wave (no barriers inside)
        f32x4 sc[2][4];
#pragma unroll
        for (int mi = 0; mi < 2; ++mi)
#pragma unroll
          for (int ni = 0; ni < 4; ++ni) sc[mi][ni] = zero;
#pragma unroll
        for (int ni = 0; ni < 4; ++ni) {
          const int krow = h * 64 + ni * 16 + l16;
          bf16x8 k0f = *(const bf16x8*)&sK[krow * 64 + ((hi ^ (l16 & 7)) * 8)];
          bf16x8 k1f = *(const bf16x8*)&sK[krow * 64 + (((4 + hi) ^ (l16 & 7)) * 8)];
#pragma unroll
          for (int mi = 0; mi < 2; ++mi) {
            sc[mi][ni] = __builtin_amdgcn_mfma_f32_16x16x32_bf16(qf[mi][0], k0f, sc[mi][ni], 0, 0, 0);
            sc[mi][ni] = __builtin_amdgcn_mfma_f32_16x16x32_bf16(qf[mi][1], k1f, sc[mi][ni], 0, 0, 0);
          }
        }
        if (c0h + 64 > q0) {  // boundary half: per-element causal mask
#pragma unroll
          for (int mi = 0; mi < 2; ++mi)
#pragma unroll
            for (int ni = 0; ni < 4; ++ni)
#pragma unroll
              for (int r = 0; r < 4; ++r) {
                int col = c0h + ni * 16 + l16;
                int row = q0 + mi * 16 + hi * 4 + r;
                if (col > row) sc[mi][ni][r] = -1e30f;
              }
        }
#pragma unroll
        for (int mi = 0; mi < 2; ++mi)
#pragma unroll
          for (int ni = 0; ni < 4; ++ni)
#pragma unroll
            for (int r = 0; r < 4; ++r) {
              float p = exp2_raw(sc[mi][ni][r]);
              sPw[(mi * 16 + hi * 4 + r) * 136 + h * 64 + ni * 16 + l16] = f2bf_trunc(p);
            }
      }
      // --- PV over the 128 cols (only valid 32-col quarters for this wave) ---
#pragma unroll
      for (int ks = 0; ks < 4; ++ks) {
        if (c0 + ks * 32 > q0) break;  // wave-uniform
        bf16x8 pa[2];
#pragma unroll
        for (int mi = 0; mi < 2; ++mi) {
          pa[mi] = *(const bf16x8*)&sPw[(mi * 16 + l16) * 136 + ks * 32 + hi * 8];
          os[mi] = __builtin_amdgcn_mfma_f32_16x16x32_bf16(pa[mi], ones, os[mi], 0, 0, 0);
        }
#pragma unroll
        for (int ni = 0; ni < 4; ++ni) {
          const int d = ni * 16 + l16;
          bf16x8 vb = *(const bf16x8*)&sV[d * 128 + (((ks * 4 + hi) ^ l16) * 8)];
#pragma unroll
          for (int mi = 0; mi < 2; ++mi)
            o[mi][ni] = __builtin_amdgcn_mfma_f32_16x16x32_bf16(pa[mi], vb, o[mi][ni], 0, 0, 0);
        }
      }
    }
    // normalize + store (row-sum already per-lane in os[mi][r]; no reduce needed)
#pragma unroll
    for (int mi = 0; mi < 2; ++mi) {
      float inv[4];
#pragma unroll
      for (int r = 0; r < 4; ++r) inv[r] = 1.f / os[mi][r];
#pragma unroll
      for (int ni = 0; ni < 4; ++ni)
#pragma unroll
        for (int r = 0; r < 4; ++r) {
          int row = q0 + mi * 16 + hi * 4 + r;
          Y[(size_t)(b * 2048 + row) * 2048 + hq * 64 + ni * 16 + l16] =
              f2bf(o[mi][ni][r] * inv[r]);
        }
    }
  }
}

// ---------- launcher ----------
extern "C" void kernel_launch(void* const* d_in, const int* in_sizes, int n_in,
                              void* d_out, int out_size, void* d_ws, size_t ws_size,
                              hipStream_t stream) {
  const float* x    = (const float*)d_in[0];   // [2,2048,2048]
  const float* wqkv = (const float*)d_in[1];   // [3072,2048]
  const float* wo   = (const float*)d_in[2];   // [2048,2048]
  float* out = (float*)d_out;                  // [2,2048,2048] f32

  char* ws = (char*)d_ws;
  unsigned short* xb   = (unsigned short*)(ws);              // [0, 16M)  x bf16; later y
  unsigned short* wqb  = (unsigned short*)(ws + 16777216);   // dead after gemm1
  unsigned short* wob  = (unsigned short*)(ws + 29360128);
  unsigned short* qkvb = (unsigned short*)(ws + 37748736);   // dead after prep
  unsigned short* qb   = (unsigned short*)(ws + 62914560);
  unsigned short* kb   = (unsigned short*)(ws + 79691776);
  unsigned short* vtb  = (unsigned short*)(ws + 83886080);   // total 88,080,384
  unsigned short* yb = xb;  // alias: x's bf16 copy is dead after the QKV GEMM

  cvt3<<<2048, 256, 0, stream>>>(x, wqkv, wo, xb, wqb, wob);
  gemm_bt<0><<<dim3(3072 / 128, 4096 / 128), 256, 0, stream>>>(xb, wqb, qkvb, 3072);
  prep<<<1152, 256, 0, stream>>>(qkvb, qb, kb, vtb);
  attn<<<dim3(64, 8), 256, 0, stream>>>(qb, kb, vtb, yb);
  gemm_bt<1><<<dim3(2048 / 128, 4096 / 128), 256, 0, stream>>>(yb, wob, out, 2048);
}